// Round 1
// baseline (1325.669 us; speedup 1.0000x reference)
//
#include <hip/hip_runtime.h>
#include <hip/hip_bf16.h>

typedef __bf16 bf16_t;
typedef __bf16 bf16x8 __attribute__((ext_vector_type(8)));
typedef float  f32x4  __attribute__((ext_vector_type(4)));

static constexpr int TT = 8192;     // tokens (2*4096)
static constexpr int DD = 1024;
static constexpr int FF = 4096;
static constexpr int NSLOT = 2 * TT;  // 16384 (token, k) slots

// routing int-array layout
#define R_COUNTS 0
#define R_OFFSET 8
#define R_TSTART 17
#define R_CURSOR 26
#define R_TOTAL  34
#define R_INTS   40

// ---------------------------------------------------------------- convert
__global__ __launch_bounds__(256) void cvt_f32_bf16(const float* __restrict__ src,
                                                    bf16_t* __restrict__ dst, int n8) {
  int i = blockIdx.x * 256 + threadIdx.x;
  if (i >= n8) return;
  const float4* s = reinterpret_cast<const float4*>(src) + (size_t)i * 2;
  float4 a = s[0], b = s[1];
  bf16x8 v;
  v[0] = (bf16_t)a.x; v[1] = (bf16_t)a.y; v[2] = (bf16_t)a.z; v[3] = (bf16_t)a.w;
  v[4] = (bf16_t)b.x; v[5] = (bf16_t)b.y; v[6] = (bf16_t)b.z; v[7] = (bf16_t)b.w;
  *reinterpret_cast<bf16x8*>(dst + (size_t)i * 8) = v;
}

// ---------------------------------------------------------------- gate
// one wave per token: 8 dot products over D=1024, softmax, top-2
__global__ __launch_bounds__(256) void gate_kernel(const float* __restrict__ x,
                                                   const float* __restrict__ gw,
                                                   float* __restrict__ topkw,
                                                   int* __restrict__ slote,
                                                   int* __restrict__ routing) {
  int wid = threadIdx.x >> 6, lane = threadIdx.x & 63;
  int t = blockIdx.x * 4 + wid;
  const float4* xv = reinterpret_cast<const float4*>(x + (size_t)t * DD) + lane * 4;
  const float4* gv = reinterpret_cast<const float4*>(gw);
  float acc[8];
#pragma unroll
  for (int e = 0; e < 8; ++e) acc[e] = 0.f;
#pragma unroll
  for (int i = 0; i < 4; ++i) {
    float4 xi = xv[i];
#pragma unroll
    for (int e = 0; e < 8; ++e) {
      float4 g = gv[e * 256 + lane * 4 + i];
      acc[e] += xi.x * g.x + xi.y * g.y + xi.z * g.z + xi.w * g.w;
    }
  }
#pragma unroll
  for (int e = 0; e < 8; ++e)
    for (int off = 32; off; off >>= 1) acc[e] += __shfl_xor(acc[e], off, 64);
  if (lane == 0) {
    float m = acc[0];
#pragma unroll
    for (int e = 1; e < 8; ++e) m = fmaxf(m, acc[e]);
    float p[8], s = 0.f;
#pragma unroll
    for (int e = 0; e < 8; ++e) { p[e] = expf(acc[e] - m); s += p[e]; }
    float inv = 1.f / s;
#pragma unroll
    for (int e = 0; e < 8; ++e) p[e] *= inv;
    int e1 = 0; float b1v = p[0];
#pragma unroll
    for (int e = 1; e < 8; ++e) if (p[e] > b1v) { b1v = p[e]; e1 = e; }
    int e2 = -1; float b2v = -1.f;
#pragma unroll
    for (int e = 0; e < 8; ++e) if (e != e1 && p[e] > b2v) { b2v = p[e]; e2 = e; }
    topkw[2 * t] = b1v;  topkw[2 * t + 1] = b2v;
    slote[2 * t] = e1;   slote[2 * t + 1] = e2;
    atomicAdd(&routing[R_COUNTS + e1], 1);
    atomicAdd(&routing[R_COUNTS + e2], 1);
  }
}

// ---------------------------------------------------------------- scan (1 thread)
__global__ void scan_kernel(int* __restrict__ routing) {
  int off = 0, tt = 0;
  for (int e = 0; e < 8; ++e) {
    routing[R_OFFSET + e] = off;
    routing[R_TSTART + e] = tt;
    int c = routing[R_COUNTS + e];
    off += c;
    tt += (c + 127) >> 7;
    routing[R_CURSOR + e] = 0;
  }
  routing[R_OFFSET + 8] = off;
  routing[R_TSTART + 8] = tt;
  routing[R_TOTAL] = tt;
}

// ---------------------------------------------------------------- scatter
__global__ __launch_bounds__(256) void scatter_kernel(const int* __restrict__ slote,
                                                      int* __restrict__ routing,
                                                      int* __restrict__ perm) {
  int s = blockIdx.x * 256 + threadIdx.x;
  int e = slote[s];
  int p = atomicAdd(&routing[R_CURSOR + e], 1);
  perm[routing[R_OFFSET + e] + p] = s;
}

// ---------------------------------------------------------------- GEMM
// MODE 0: expert G1  (A = x_bf16 gathered via perm, K=1024) -> GELU -> H (bf16)
// MODE 1: expert G2  (A = H rows,                K=4096) -> w*( . +b2) atomicAdd out
// MODE 2: shared G1  (A = x_bf16 direct,         K=1024) -> GELU -> H (bf16)
// MODE 3: shared G2  (A = H rows,                K=4096) -> plain store out (+sb2)
template <int MODE>
__global__ __launch_bounds__(256) void gemm_kernel(
    const bf16_t* __restrict__ A, const bf16_t* __restrict__ Bw,
    const float* __restrict__ bias, bf16_t* __restrict__ Hout,
    float* __restrict__ out, const int* __restrict__ routing,
    const int* __restrict__ perm, const float* __restrict__ topkw) {
  constexpr bool G1 = (MODE == 0 || MODE == 2);
  constexpr bool EXPERT = (MODE < 2);
  constexpr int K = G1 ? 1024 : 4096;
  constexpr int NTOT = G1 ? 4096 : 1024;

  __shared__ __align__(16) bf16_t ldsA[128 * 64];
  __shared__ __align__(16) bf16_t ldsB[128 * 64];

  const int tid = threadIdx.x;
  const int lane = tid & 63;
  const int wid = tid >> 6;
  const int wm = wid >> 1, wn = wid & 1;

  int row0, valid, eidx = 0;
  if constexpr (EXPERT) {
    int mt = blockIdx.x;
    if (mt >= routing[R_TOTAL]) return;
    int e = 0;
    while (e < 7 && routing[R_TSTART + e + 1] <= mt) ++e;
    eidx = e;
    int lm = mt - routing[R_TSTART + e];
    row0 = routing[R_OFFSET + e] + lm * 128;
    valid = min(128, routing[R_COUNTS + e] - lm * 128);
  } else {
    row0 = blockIdx.x * 128;
    valid = 128;
  }
  const int nt = blockIdx.y;

  const bf16_t* Bexp = Bw + (EXPERT ? (size_t)eidx * NTOT * K : 0);
  const float* biasp = bias + (EXPERT ? eidx * NTOT : 0);

  // staging source rows: thread tid covers tile element i*2048 + tid*8
  // LDS linear (row, chunk); source chunk = chunk ^ (row&7)  [both-sides swizzle]
  const int schunk = (tid & 7) ^ ((tid >> 3) & 7);
  const bf16_t* aRow[4];
  const bf16_t* bRow[4];
#pragma unroll
  for (int i = 0; i < 4; ++i) {
    int r = i * 32 + (tid >> 3);
    int ar;
    if constexpr (MODE == 0) {
      ar = perm[row0 + min(r, valid - 1)] >> 1;  // token index
    } else if constexpr (MODE == 1) {
      ar = row0 + min(r, valid - 1);             // H row
    } else {
      ar = row0 + r;
    }
    aRow[i] = A + (size_t)ar * K + schunk * 8;
    bRow[i] = Bexp + (size_t)(nt * 128 + r) * K + schunk * 8;
  }
  bf16_t* ldsAd = &ldsA[wid * 512];
  bf16_t* ldsBd = &ldsB[wid * 512];

  f32x4 acc[4][4];
#pragma unroll
  for (int m = 0; m < 4; ++m)
#pragma unroll
    for (int n = 0; n < 4; ++n) acc[m][n] = f32x4{0.f, 0.f, 0.f, 0.f};

  for (int kt = 0; kt < K / 64; ++kt) {
    const int kof = kt * 64;
#pragma unroll
    for (int i = 0; i < 4; ++i) {
      __builtin_amdgcn_global_load_lds(
          (__attribute__((address_space(1))) void*)(aRow[i] + kof),
          (__attribute__((address_space(3))) void*)(ldsAd + i * 2048), 16, 0, 0);
      __builtin_amdgcn_global_load_lds(
          (__attribute__((address_space(1))) void*)(bRow[i] + kof),
          (__attribute__((address_space(3))) void*)(ldsBd + i * 2048), 16, 0, 0);
    }
    __syncthreads();  // drains vmcnt for the LDS-DMA, then barrier
#pragma unroll
    for (int kk = 0; kk < 2; ++kk) {
      bf16x8 af[4], bfr[4];
#pragma unroll
      for (int m = 0; m < 4; ++m) {
        int ra = wm * 64 + m * 16 + (lane & 15);
        int c = (kk * 4 + (lane >> 4)) ^ (ra & 7);
        af[m] = *reinterpret_cast<const bf16x8*>(&ldsA[ra * 64 + c * 8]);
      }
#pragma unroll
      for (int n = 0; n < 4; ++n) {
        int rb = wn * 64 + n * 16 + (lane & 15);
        int c = (kk * 4 + (lane >> 4)) ^ (rb & 7);
        bfr[n] = *reinterpret_cast<const bf16x8*>(&ldsB[rb * 64 + c * 8]);
      }
#pragma unroll
      for (int m = 0; m < 4; ++m)
#pragma unroll
        for (int n = 0; n < 4; ++n)
          acc[m][n] = __builtin_amdgcn_mfma_f32_16x16x32_bf16(af[m], bfr[n], acc[m][n], 0, 0, 0);
    }
    __syncthreads();
  }

  // epilogue.  C/D: col = lane&15, row = (lane>>4)*4 + reg  [m89-verified]
  if constexpr (G1) {
#pragma unroll
    for (int n = 0; n < 4; ++n) {
      int col = nt * 128 + wn * 64 + n * 16 + (lane & 15);
      float bc = biasp[col];
#pragma unroll
      for (int m = 0; m < 4; ++m) {
        int lrb = wm * 64 + m * 16 + ((lane >> 4) << 2);
#pragma unroll
        for (int r = 0; r < 4; ++r) {
          int lr = lrb + r;
          if (lr < valid) {
            float v = acc[m][n][r] + bc;
            float h = 0.5f * v * (1.f + erff(v * 0.70710678118f));
            Hout[(size_t)(row0 + lr) * FF + col] = (bf16_t)h;
          }
        }
      }
    }
  } else if constexpr (MODE == 1) {
#pragma unroll
    for (int m = 0; m < 4; ++m) {
      int lrb = wm * 64 + m * 16 + ((lane >> 4) << 2);
#pragma unroll
      for (int r = 0; r < 4; ++r) {
        int lr = lrb + r;
        if (lr >= valid) continue;
        int s = perm[row0 + lr];
        int tok = s >> 1;
        float w = topkw[s];
#pragma unroll
        for (int n = 0; n < 4; ++n) {
          int col = nt * 128 + wn * 64 + n * 16 + (lane & 15);
          float v = acc[m][n][r] + biasp[col];
          atomicAdd(&out[(size_t)tok * DD + col], w * v);
        }
      }
    }
  } else {
#pragma unroll
    for (int m = 0; m < 4; ++m) {
      int lrb = wm * 64 + m * 16 + ((lane >> 4) << 2);
#pragma unroll
      for (int r = 0; r < 4; ++r) {
        int lr = lrb + r;
#pragma unroll
        for (int n = 0; n < 4; ++n) {
          int col = nt * 128 + wn * 64 + n * 16 + (lane & 15);
          out[(size_t)(row0 + lr) * DD + col] = acc[m][n][r] + biasp[col];
        }
      }
    }
  }
}

// ---------------------------------------------------------------- launch
extern "C" void kernel_launch(void* const* d_in, const int* in_sizes, int n_in,
                              void* d_out, int out_size, void* d_ws, size_t ws_size,
                              hipStream_t stream) {
  const float* x   = (const float*)d_in[0];
  const float* gw  = (const float*)d_in[1];
  const float* w1  = (const float*)d_in[2];
  const float* b1  = (const float*)d_in[3];
  const float* w2  = (const float*)d_in[4];
  const float* b2  = (const float*)d_in[5];
  const float* sw1 = (const float*)d_in[6];
  const float* sb1 = (const float*)d_in[7];
  const float* sw2 = (const float*)d_in[8];
  const float* sb2 = (const float*)d_in[9];
  float* out = (float*)d_out;

  char* ws = (char*)d_ws;
  bf16_t* xb    = (bf16_t*)(ws);                          // 16 MB
  bf16_t* w1b   = (bf16_t*)(ws + ((size_t)16 << 20));     // 64 MB
  bf16_t* w2b   = (bf16_t*)(ws + ((size_t)80 << 20));     // 64 MB
  bf16_t* sw1b  = (bf16_t*)(ws + ((size_t)144 << 20));    // 8 MB
  bf16_t* sw2b  = (bf16_t*)(ws + ((size_t)152 << 20));    // 8 MB
  bf16_t* Hbuf  = (bf16_t*)(ws + ((size_t)160 << 20));    // 128 MB (16384 x 4096 bf16)
  float*  topkw = (float*)(ws + ((size_t)288 << 20));     // 64 KB
  int*    slote = (int*)(ws + ((size_t)288 << 20) + 65536);
  int*    perm  = (int*)(ws + ((size_t)288 << 20) + 2 * 65536);
  int*    routing = (int*)(ws + ((size_t)288 << 20) + 3 * 65536);

  hipMemsetAsync(routing, 0, R_INTS * sizeof(int), stream);

  // fp32 -> bf16 conversions
  cvt_f32_bf16<<<(TT * DD / 8 + 255) / 256, 256, 0, stream>>>(x, xb, TT * DD / 8);
  cvt_f32_bf16<<<(8 * FF * DD / 8 + 255) / 256, 256, 0, stream>>>(w1, w1b, 8 * FF * DD / 8);
  cvt_f32_bf16<<<(8 * DD * FF / 8 + 255) / 256, 256, 0, stream>>>(w2, w2b, 8 * DD * FF / 8);
  cvt_f32_bf16<<<(FF * DD / 8 + 255) / 256, 256, 0, stream>>>(sw1, sw1b, FF * DD / 8);
  cvt_f32_bf16<<<(DD * FF / 8 + 255) / 256, 256, 0, stream>>>(sw2, sw2b, DD * FF / 8);

  // routing
  gate_kernel<<<TT / 4, 256, 0, stream>>>(x, gw, topkw, slote, routing);
  scan_kernel<<<1, 1, 0, stream>>>(routing);
  scatter_kernel<<<NSLOT / 256, 256, 0, stream>>>(slote, routing, perm);

  // shared expert: writes every out element (plain store), then experts atomicAdd
  gemm_kernel<2><<<dim3(64, 32), 256, 0, stream>>>(xb, sw1b, sb1, Hbuf, out, routing, perm, topkw);
  gemm_kernel<3><<<dim3(64, 8), 256, 0, stream>>>(Hbuf, sw2b, sb2, nullptr, out, routing, perm, topkw);
  gemm_kernel<0><<<dim3(136, 32), 256, 0, stream>>>(xb, w1b, b1, Hbuf, out, routing, perm, topkw);
  gemm_kernel<1><<<dim3(136, 8), 256, 0, stream>>>(Hbuf, w2b, b2, nullptr, out, routing, perm, topkw);
}

// Round 2
// 1179.824 us; speedup vs baseline: 1.1236x; 1.1236x over previous
//
#include <hip/hip_runtime.h>
#include <hip/hip_bf16.h>

typedef __bf16 bf16_t;
typedef __bf16 bf16x8 __attribute__((ext_vector_type(8)));
typedef float  f32x4  __attribute__((ext_vector_type(4)));

static constexpr int TT = 8192;     // tokens (2*4096)
static constexpr int DD = 1024;
static constexpr int FF = 4096;
static constexpr int NSLOT = 2 * TT;  // 16384 (token, k) slots

// routing int-array layout
#define R_COUNTS 0
#define R_OFFSET 8
#define R_TSTART 17
#define R_CURSOR 26
#define R_TOTAL  34
#define R_INTS   40

__device__ __forceinline__ float fast_gelu(float v) {
  // tanh-form GELU: v * sigmoid(1.59577*(v + 0.044715 v^3)); max dev vs erf ~3e-4
  float t = -1.5957691216f * v - 0.0713548162f * (v * v * v);
  return v / (1.f + __expf(t));
}

// ---------------------------------------------------------------- convert
__global__ __launch_bounds__(256) void cvt_f32_bf16(const float* __restrict__ src,
                                                    bf16_t* __restrict__ dst, int n8) {
  int i = blockIdx.x * 256 + threadIdx.x;
  if (i >= n8) return;
  const float4* s = reinterpret_cast<const float4*>(src) + (size_t)i * 2;
  float4 a = s[0], b = s[1];
  bf16x8 v;
  v[0] = (bf16_t)a.x; v[1] = (bf16_t)a.y; v[2] = (bf16_t)a.z; v[3] = (bf16_t)a.w;
  v[4] = (bf16_t)b.x; v[5] = (bf16_t)b.y; v[6] = (bf16_t)b.z; v[7] = (bf16_t)b.w;
  *reinterpret_cast<bf16x8*>(dst + (size_t)i * 8) = v;
}

// ---------------------------------------------------------------- gate
__global__ __launch_bounds__(256) void gate_kernel(const float* __restrict__ x,
                                                   const float* __restrict__ gw,
                                                   float* __restrict__ topkw,
                                                   int* __restrict__ slote,
                                                   int* __restrict__ routing) {
  int wid = threadIdx.x >> 6, lane = threadIdx.x & 63;
  int t = blockIdx.x * 4 + wid;
  const float4* xv = reinterpret_cast<const float4*>(x + (size_t)t * DD) + lane * 4;
  const float4* gv = reinterpret_cast<const float4*>(gw);
  float acc[8];
#pragma unroll
  for (int e = 0; e < 8; ++e) acc[e] = 0.f;
#pragma unroll
  for (int i = 0; i < 4; ++i) {
    float4 xi = xv[i];
#pragma unroll
    for (int e = 0; e < 8; ++e) {
      float4 g = gv[e * 256 + lane * 4 + i];
      acc[e] += xi.x * g.x + xi.y * g.y + xi.z * g.z + xi.w * g.w;
    }
  }
#pragma unroll
  for (int e = 0; e < 8; ++e)
    for (int off = 32; off; off >>= 1) acc[e] += __shfl_xor(acc[e], off, 64);
  if (lane == 0) {
    float m = acc[0];
#pragma unroll
    for (int e = 1; e < 8; ++e) m = fmaxf(m, acc[e]);
    float p[8], s = 0.f;
#pragma unroll
    for (int e = 0; e < 8; ++e) { p[e] = expf(acc[e] - m); s += p[e]; }
    float inv = 1.f / s;
#pragma unroll
    for (int e = 0; e < 8; ++e) p[e] *= inv;
    int e1 = 0; float b1v = p[0];
#pragma unroll
    for (int e = 1; e < 8; ++e) if (p[e] > b1v) { b1v = p[e]; e1 = e; }
    int e2 = -1; float b2v = -1.f;
#pragma unroll
    for (int e = 0; e < 8; ++e) if (e != e1 && p[e] > b2v) { b2v = p[e]; e2 = e; }
    topkw[2 * t] = b1v;  topkw[2 * t + 1] = b2v;
    slote[2 * t] = e1;   slote[2 * t + 1] = e2;
    atomicAdd(&routing[R_COUNTS + e1], 1);
    atomicAdd(&routing[R_COUNTS + e2], 1);
  }
}

// ---------------------------------------------------------------- scan (1 thread)
__global__ void scan_kernel(int* __restrict__ routing) {
  int off = 0, tt = 0;
  for (int e = 0; e < 8; ++e) {
    routing[R_OFFSET + e] = off;
    routing[R_TSTART + e] = tt;
    int c = routing[R_COUNTS + e];
    off += c;
    tt += (c + 127) >> 7;
    routing[R_CURSOR + e] = 0;
  }
  routing[R_OFFSET + 8] = off;
  routing[R_TSTART + 8] = tt;
  routing[R_TOTAL] = tt;
}

// ---------------------------------------------------------------- scatter
__global__ __launch_bounds__(256) void scatter_kernel(const int* __restrict__ slote,
                                                      int* __restrict__ routing,
                                                      int* __restrict__ perm,
                                                      int* __restrict__ pos) {
  int s = blockIdx.x * 256 + threadIdx.x;
  int e = slote[s];
  int p = atomicAdd(&routing[R_CURSOR + e], 1);
  int pp = routing[R_OFFSET + e] + p;
  perm[pp] = s;
  pos[s] = pp;
}

// ---------------------------------------------------------------- combine
// out[t,c] = shared(t,c) [already in out] + w0*slot[pos0,c] + w1*slot[pos1,c]
__global__ __launch_bounds__(256) void combine_kernel(const float* __restrict__ slotbuf,
                                                      const int* __restrict__ pos,
                                                      const float* __restrict__ topkw,
                                                      float* __restrict__ out) {
  int idx = blockIdx.x * 256 + threadIdx.x;   // one float4 per thread
  int t = idx >> 8;                            // DD/4 = 256 float4 per token
  int c = (idx & 255) << 2;
  int p0 = pos[2 * t], p1 = pos[2 * t + 1];
  float w0 = topkw[2 * t], w1 = topkw[2 * t + 1];
  float4 o = *reinterpret_cast<const float4*>(&out[(size_t)t * DD + c]);
  float4 s0 = *reinterpret_cast<const float4*>(&slotbuf[(size_t)p0 * DD + c]);
  float4 s1 = *reinterpret_cast<const float4*>(&slotbuf[(size_t)p1 * DD + c]);
  o.x += w0 * s0.x + w1 * s1.x;
  o.y += w0 * s0.y + w1 * s1.y;
  o.z += w0 * s0.z + w1 * s1.z;
  o.w += w0 * s0.w + w1 * s1.w;
  *reinterpret_cast<float4*>(&out[(size_t)t * DD + c]) = o;
}

// ---------------------------------------------------------------- GEMM
// MODE 0: expert G1  (A = x_bf16 gathered via perm, K=1024) -> fast_gelu -> H (bf16)
// MODE 1: expert G2  (A = H rows,                K=4096) -> (.+b2) store slotbuf (fp32)
// MODE 2: shared G1  (A = x_bf16 direct,         K=1024) -> fast_gelu -> H (bf16)
// MODE 3: shared G2  (A = H rows,                K=4096) -> plain store out (+sb2)
template <int MODE>
__global__ __launch_bounds__(256) void gemm_kernel(
    const bf16_t* __restrict__ A, const bf16_t* __restrict__ Bw,
    const float* __restrict__ bias, bf16_t* __restrict__ Hout,
    float* __restrict__ out, const int* __restrict__ routing,
    const int* __restrict__ perm) {
  constexpr bool G1 = (MODE == 0 || MODE == 2);
  constexpr bool EXPERT = (MODE < 2);
  constexpr int K = G1 ? 1024 : 4096;
  constexpr int NTOT = G1 ? 4096 : 1024;
  constexpr int NT = NTOT / 128;  // 32 or 8 (power of two)

  __shared__ __align__(16) bf16_t ldsA[128 * 64];
  __shared__ __align__(16) bf16_t ldsB[128 * 64];

  const int tid = threadIdx.x;
  const int lane = tid & 63;
  const int wid = tid >> 6;
  const int wm = wid >> 1, wn = wid & 1;

  // ---- block decode: bijective XCD swizzle, then nt-fastest (share A panel)
  const int nwg = gridDim.x;
  const int q = nwg >> 3, r = nwg & 7;
  const int xcd = blockIdx.x & 7, bi = blockIdx.x >> 3;
  const int swz = (xcd < r ? xcd * (q + 1) : r * (q + 1) + (xcd - r) * q) + bi;
  const int mt = swz / NT;
  const int nt = swz & (NT - 1);

  int row0, valid, eidx = 0;
  if constexpr (EXPERT) {
    if (mt >= routing[R_TOTAL]) return;
    int e = 0;
    while (e < 7 && routing[R_TSTART + e + 1] <= mt) ++e;
    eidx = e;
    int lm = mt - routing[R_TSTART + e];
    row0 = routing[R_OFFSET + e] + lm * 128;
    valid = min(128, routing[R_COUNTS + e] - lm * 128);
  } else {
    row0 = mt * 128;
    valid = 128;
  }

  const bf16_t* Bexp = Bw + (EXPERT ? (size_t)eidx * NTOT * K : 0);
  const float* biasp = bias + (EXPERT ? eidx * NTOT : 0);

  // staging: LDS linear (row, chunk); source chunk = chunk ^ (row&7) [both-sides swizzle]
  const int schunk = (tid & 7) ^ ((tid >> 3) & 7);
  const bf16_t* aRow[4];
  const bf16_t* bRow[4];
#pragma unroll
  for (int i = 0; i < 4; ++i) {
    int rr = i * 32 + (tid >> 3);
    int ar;
    if constexpr (MODE == 0) {
      ar = perm[row0 + min(rr, valid - 1)] >> 1;  // token index
    } else if constexpr (MODE == 1) {
      ar = row0 + min(rr, valid - 1);             // H row (position-indexed)
    } else {
      ar = row0 + rr;
    }
    aRow[i] = A + (size_t)ar * K + schunk * 8;
    bRow[i] = Bexp + (size_t)(nt * 128 + rr) * K + schunk * 8;
  }
  bf16_t* ldsAd = &ldsA[wid * 512];
  bf16_t* ldsBd = &ldsB[wid * 512];

  f32x4 acc[4][4];
#pragma unroll
  for (int m = 0; m < 4; ++m)
#pragma unroll
    for (int n = 0; n < 4; ++n) acc[m][n] = f32x4{0.f, 0.f, 0.f, 0.f};

  for (int kt = 0; kt < K / 64; ++kt) {
    const int kof = kt * 64;
#pragma unroll
    for (int i = 0; i < 4; ++i) {
      __builtin_amdgcn_global_load_lds(
          (__attribute__((address_space(1))) void*)(aRow[i] + kof),
          (__attribute__((address_space(3))) void*)(ldsAd + i * 2048), 16, 0, 0);
      __builtin_amdgcn_global_load_lds(
          (__attribute__((address_space(1))) void*)(bRow[i] + kof),
          (__attribute__((address_space(3))) void*)(ldsBd + i * 2048), 16, 0, 0);
    }
    __syncthreads();  // drains vmcnt for the LDS-DMA, then barrier
#pragma unroll
    for (int kk = 0; kk < 2; ++kk) {
      bf16x8 af[4], bfr[4];
#pragma unroll
      for (int m = 0; m < 4; ++m) {
        int ra = wm * 64 + m * 16 + (lane & 15);
        int c = (kk * 4 + (lane >> 4)) ^ (ra & 7);
        af[m] = *reinterpret_cast<const bf16x8*>(&ldsA[ra * 64 + c * 8]);
      }
#pragma unroll
      for (int n = 0; n < 4; ++n) {
        int rb = wn * 64 + n * 16 + (lane & 15);
        int c = (kk * 4 + (lane >> 4)) ^ (rb & 7);
        bfr[n] = *reinterpret_cast<const bf16x8*>(&ldsB[rb * 64 + c * 8]);
      }
#pragma unroll
      for (int m = 0; m < 4; ++m)
#pragma unroll
        for (int n = 0; n < 4; ++n)
          acc[m][n] = __builtin_amdgcn_mfma_f32_16x16x32_bf16(af[m], bfr[n], acc[m][n], 0, 0, 0);
    }
    __syncthreads();
  }

  // epilogue.  C/D: col = lane&15, row = (lane>>4)*4 + reg  [m89-verified]
  if constexpr (G1) {
#pragma unroll
    for (int n = 0; n < 4; ++n) {
      int col = nt * 128 + wn * 64 + n * 16 + (lane & 15);
      float bc = biasp[col];
#pragma unroll
      for (int m = 0; m < 4; ++m) {
        int lrb = wm * 64 + m * 16 + ((lane >> 4) << 2);
#pragma unroll
        for (int r = 0; r < 4; ++r) {
          int lr = lrb + r;
          if (lr < valid) {
            float v = acc[m][n][r] + bc;
            Hout[(size_t)(row0 + lr) * FF + col] = (bf16_t)fast_gelu(v);
          }
        }
      }
    }
  } else {
    // MODE 1: store to slotbuf (position-indexed); MODE 3: store to out
#pragma unroll
    for (int m = 0; m < 4; ++m) {
      int lrb = wm * 64 + m * 16 + ((lane >> 4) << 2);
#pragma unroll
      for (int r = 0; r < 4; ++r) {
        int lr = lrb + r;
        if (lr >= valid) continue;
#pragma unroll
        for (int n = 0; n < 4; ++n) {
          int col = nt * 128 + wn * 64 + n * 16 + (lane & 15);
          out[(size_t)(row0 + lr) * DD + col] = acc[m][n][r] + biasp[col];
        }
      }
    }
  }
}

// ---------------------------------------------------------------- launch
extern "C" void kernel_launch(void* const* d_in, const int* in_sizes, int n_in,
                              void* d_out, int out_size, void* d_ws, size_t ws_size,
                              hipStream_t stream) {
  const float* x   = (const float*)d_in[0];
  const float* gw  = (const float*)d_in[1];
  const float* w1  = (const float*)d_in[2];
  const float* b1  = (const float*)d_in[3];
  const float* w2  = (const float*)d_in[4];
  const float* b2  = (const float*)d_in[5];
  const float* sw1 = (const float*)d_in[6];
  const float* sb1 = (const float*)d_in[7];
  const float* sw2 = (const float*)d_in[8];
  const float* sb2 = (const float*)d_in[9];
  float* out = (float*)d_out;

  char* ws = (char*)d_ws;
  bf16_t* xb    = (bf16_t*)(ws);                          // 16 MB  [dead after expert G1]
  bf16_t* w1b   = (bf16_t*)(ws + ((size_t)16 << 20));     // 64 MB  [dead after expert G1]
  bf16_t* w2b   = (bf16_t*)(ws + ((size_t)80 << 20));     // 64 MB
  bf16_t* sw1b  = (bf16_t*)(ws + ((size_t)144 << 20));    // 8 MB
  bf16_t* sw2b  = (bf16_t*)(ws + ((size_t)152 << 20));    // 8 MB
  bf16_t* Hbuf  = (bf16_t*)(ws + ((size_t)160 << 20));    // 128 MB (16384 x 4096 bf16)
  float*  slotbuf = (float*)(ws);                         // 67 MB, overlaps xb+w1b (dead by then)
  float*  topkw = (float*)(ws + ((size_t)288 << 20));     // 64 KB
  int*    slote = (int*)(ws + ((size_t)288 << 20) + 65536);
  int*    perm  = (int*)(ws + ((size_t)288 << 20) + 2 * 65536);
  int*    pos   = (int*)(ws + ((size_t)288 << 20) + 3 * 65536);
  int*    routing = (int*)(ws + ((size_t)288 << 20) + 4 * 65536);

  hipMemsetAsync(routing, 0, R_INTS * sizeof(int), stream);

  // fp32 -> bf16 conversions
  cvt_f32_bf16<<<(TT * DD / 8 + 255) / 256, 256, 0, stream>>>(x, xb, TT * DD / 8);
  cvt_f32_bf16<<<(8 * FF * DD / 8 + 255) / 256, 256, 0, stream>>>(w1, w1b, 8 * FF * DD / 8);
  cvt_f32_bf16<<<(8 * DD * FF / 8 + 255) / 256, 256, 0, stream>>>(w2, w2b, 8 * DD * FF / 8);
  cvt_f32_bf16<<<(FF * DD / 8 + 255) / 256, 256, 0, stream>>>(sw1, sw1b, FF * DD / 8);
  cvt_f32_bf16<<<(DD * FF / 8 + 255) / 256, 256, 0, stream>>>(sw2, sw2b, DD * FF / 8);

  // routing
  gate_kernel<<<TT / 4, 256, 0, stream>>>(x, gw, topkw, slote, routing);
  scan_kernel<<<1, 1, 0, stream>>>(routing);
  scatter_kernel<<<NSLOT / 256, 256, 0, stream>>>(slote, routing, perm, pos);

  // shared expert first (plain store covers all of out), then experts into slotbuf
  gemm_kernel<2><<<64 * 32, 256, 0, stream>>>(xb, sw1b, sb1, Hbuf, out, routing, perm);
  gemm_kernel<3><<<64 * 8, 256, 0, stream>>>(Hbuf, sw2b, sb2, nullptr, out, routing, perm);
  gemm_kernel<0><<<136 * 32, 256, 0, stream>>>(xb, w1b, b1, Hbuf, out, routing, perm);
  gemm_kernel<1><<<136 * 8, 256, 0, stream>>>(Hbuf, w2b, b2, nullptr, slotbuf, routing, perm);

  // out += gate-weighted expert contributions
  combine_kernel<<<TT, 256, 0, stream>>>(slotbuf, pos, topkw, out);
}

// Round 3
// 1136.650 us; speedup vs baseline: 1.1663x; 1.0380x over previous
//
#include <hip/hip_runtime.h>
#include <hip/hip_bf16.h>

typedef __bf16 bf16_t;
typedef __bf16 bf16x8 __attribute__((ext_vector_type(8)));
typedef float  f32x4  __attribute__((ext_vector_type(4)));

static constexpr int TT = 8192;     // tokens (2*4096)
static constexpr int DD = 1024;
static constexpr int FF = 4096;
static constexpr int NSLOT = 2 * TT;  // 16384 (token, k) slots

// routing int-array layout
#define R_COUNTS 0
#define R_OFFSET 8
#define R_TSTART 17
#define R_CURSOR 26
#define R_TOTAL  34
#define R_INTS   40

#define GLL(g, l) __builtin_amdgcn_global_load_lds( \
    (__attribute__((address_space(1))) void*)(g), \
    (__attribute__((address_space(3))) void*)(l), 16, 0, 0)

__device__ __forceinline__ float fast_gelu(float v) {
  float t = -1.5957691216f * v - 0.0713548162f * (v * v * v);
  return v / (1.f + __expf(t));
}

// ---------------------------------------------------------------- convert
__global__ __launch_bounds__(256) void cvt_f32_bf16(const float* __restrict__ src,
                                                    bf16_t* __restrict__ dst, int n8) {
  int i = blockIdx.x * 256 + threadIdx.x;
  if (i >= n8) return;
  const float4* s = reinterpret_cast<const float4*>(src) + (size_t)i * 2;
  float4 a = s[0], b = s[1];
  bf16x8 v;
  v[0] = (bf16_t)a.x; v[1] = (bf16_t)a.y; v[2] = (bf16_t)a.z; v[3] = (bf16_t)a.w;
  v[4] = (bf16_t)b.x; v[5] = (bf16_t)b.y; v[6] = (bf16_t)b.z; v[7] = (bf16_t)b.w;
  *reinterpret_cast<bf16x8*>(dst + (size_t)i * 8) = v;
}

// ---------------------------------------------------------------- gate
__global__ __launch_bounds__(256) void gate_kernel(const float* __restrict__ x,
                                                   const float* __restrict__ gw,
                                                   float* __restrict__ topkw,
                                                   int* __restrict__ slote,
                                                   int* __restrict__ routing) {
  int wid = threadIdx.x >> 6, lane = threadIdx.x & 63;
  int t = blockIdx.x * 4 + wid;
  const float4* xv = reinterpret_cast<const float4*>(x + (size_t)t * DD) + lane * 4;
  const float4* gv = reinterpret_cast<const float4*>(gw);
  float acc[8];
#pragma unroll
  for (int e = 0; e < 8; ++e) acc[e] = 0.f;
#pragma unroll
  for (int i = 0; i < 4; ++i) {
    float4 xi = xv[i];
#pragma unroll
    for (int e = 0; e < 8; ++e) {
      float4 g = gv[e * 256 + lane * 4 + i];
      acc[e] += xi.x * g.x + xi.y * g.y + xi.z * g.z + xi.w * g.w;
    }
  }
#pragma unroll
  for (int e = 0; e < 8; ++e)
    for (int off = 32; off; off >>= 1) acc[e] += __shfl_xor(acc[e], off, 64);
  if (lane == 0) {
    float m = acc[0];
#pragma unroll
    for (int e = 1; e < 8; ++e) m = fmaxf(m, acc[e]);
    float p[8], s = 0.f;
#pragma unroll
    for (int e = 0; e < 8; ++e) { p[e] = expf(acc[e] - m); s += p[e]; }
    float inv = 1.f / s;
#pragma unroll
    for (int e = 0; e < 8; ++e) p[e] *= inv;
    int e1 = 0; float b1v = p[0];
#pragma unroll
    for (int e = 1; e < 8; ++e) if (p[e] > b1v) { b1v = p[e]; e1 = e; }
    int e2 = -1; float b2v = -1.f;
#pragma unroll
    for (int e = 0; e < 8; ++e) if (e != e1 && p[e] > b2v) { b2v = p[e]; e2 = e; }
    topkw[2 * t] = b1v;  topkw[2 * t + 1] = b2v;
    slote[2 * t] = e1;   slote[2 * t + 1] = e2;
    atomicAdd(&routing[R_COUNTS + e1], 1);
    atomicAdd(&routing[R_COUNTS + e2], 1);
  }
}

// ---------------------------------------------------------------- scan (1 thread)
__global__ void scan_kernel(int* __restrict__ routing) {
  int off = 0, tt = 0;
  for (int e = 0; e < 8; ++e) {
    routing[R_OFFSET + e] = off;
    routing[R_TSTART + e] = tt;
    int c = routing[R_COUNTS + e];
    off += c;
    tt += (c + 255) >> 8;   // 256-row M-tiles
    routing[R_CURSOR + e] = 0;
  }
  routing[R_OFFSET + 8] = off;
  routing[R_TSTART + 8] = tt;
  routing[R_TOTAL] = tt;
}

// ---------------------------------------------------------------- scatter
__global__ __launch_bounds__(256) void scatter_kernel(const int* __restrict__ slote,
                                                      int* __restrict__ routing,
                                                      int* __restrict__ perm,
                                                      int* __restrict__ pos) {
  int s = blockIdx.x * 256 + threadIdx.x;
  int e = slote[s];
  int p = atomicAdd(&routing[R_CURSOR + e], 1);
  int pp = routing[R_OFFSET + e] + p;
  perm[pp] = s;
  pos[s] = pp;
}

// ---------------------------------------------------------------- combine
__global__ __launch_bounds__(256) void combine_kernel(const float* __restrict__ slotbuf,
                                                      const int* __restrict__ pos,
                                                      const float* __restrict__ topkw,
                                                      float* __restrict__ out) {
  int idx = blockIdx.x * 256 + threadIdx.x;   // one float4 per thread
  int t = idx >> 8;                            // DD/4 = 256 float4 per token
  int c = (idx & 255) << 2;
  int p0 = pos[2 * t], p1 = pos[2 * t + 1];
  float w0 = topkw[2 * t], w1 = topkw[2 * t + 1];
  float4 o = *reinterpret_cast<const float4*>(&out[(size_t)t * DD + c]);
  float4 s0 = *reinterpret_cast<const float4*>(&slotbuf[(size_t)p0 * DD + c]);
  float4 s1 = *reinterpret_cast<const float4*>(&slotbuf[(size_t)p1 * DD + c]);
  o.x += w0 * s0.x + w1 * s1.x;
  o.y += w0 * s0.y + w1 * s1.y;
  o.z += w0 * s0.z + w1 * s1.z;
  o.w += w0 * s0.w + w1 * s1.w;
  *reinterpret_cast<float4*>(&out[(size_t)t * DD + c]) = o;
}

// ---------------------------------------------------------------- GEMM (pipelined 256x256, BK=32, ring-4)
// MODE 0: expert G1 (A gathered via perm, K=1024) -> fast_gelu -> H (bf16)
// MODE 1: expert G2 (A = H rows, K=4096)          -> (.+b2) store slotbuf fp32
// MODE 2: shared G1 (A = x direct, K=1024)        -> fast_gelu -> H (bf16)
// MODE 3: shared G2 (A = H rows, K=4096)          -> plain store out (+sb2)
template <int MODE>
__global__ __launch_bounds__(512, 2) void gemm_kernel(
    const bf16_t* __restrict__ A, const bf16_t* __restrict__ Bw,
    const float* __restrict__ bias, bf16_t* __restrict__ Hout,
    float* __restrict__ out, const int* __restrict__ routing,
    const int* __restrict__ perm) {
  constexpr bool G1 = (MODE == 0 || MODE == 2);
  constexpr bool EXPERT = (MODE < 2);
  constexpr int K = G1 ? 1024 : 4096;
  constexpr int NTOT = G1 ? 4096 : 1024;
  constexpr int NT = NTOT / 256;   // 16 or 4
  constexpr int NK = K / 32;       // 32 or 128

  // ring of 4 buffers: [buf][A:256x32 | B:256x32] bf16 = 4 * 32KB = 128KB
  __shared__ __align__(16) bf16_t lds[4 * 16384];

  const int t = threadIdx.x;
  const int lane = t & 63;
  const int wid = t >> 6;          // 0..7
  const int wm = wid >> 2;         // 0..1  (128-row half)
  const int wn = wid & 3;          // 0..3  (64-col quarter)

  // ---- block decode: bijective XCD swizzle, nt-fastest
  const int nwg = gridDim.x;
  const int q = nwg >> 3, r = nwg & 7;
  const int xcd = blockIdx.x & 7, bi = blockIdx.x >> 3;
  const int swz = (xcd < r ? xcd * (q + 1) : r * (q + 1) + (xcd - r) * q) + bi;
  const int mt = swz / NT;
  const int nt = swz % NT;

  int row0, valid, eidx = 0;
  if constexpr (EXPERT) {
    if (mt >= routing[R_TOTAL]) return;
    int e = 0;
    while (e < 7 && routing[R_TSTART + e + 1] <= mt) ++e;
    eidx = e;
    int lm = mt - routing[R_TSTART + e];
    row0 = routing[R_OFFSET + e] + lm * 256;
    valid = min(256, routing[R_COUNTS + e] - lm * 256);
  } else {
    row0 = mt * 256;
    valid = 256;
  }

  const bf16_t* Bexp = Bw + (EXPERT ? (size_t)eidx * NTOT * K : 0);
  const float* biasp = bias + (EXPERT ? eidx * NTOT : 0);

  // ---- staging source pointers. thread t covers (row = t>>2, chunk = t&3)
  // LDS linear; source chunk pre-swizzled: sc = (t&3) ^ (row&3)
  const int srow = t >> 2;
  const int sc = (t & 3) ^ (srow & 3);
  const bf16_t *aSrc0, *aSrc1, *bSrc0, *bSrc1;
  {
    int lr0 = srow, lr1 = 128 + srow;
    int gr0, gr1;
    if constexpr (MODE == 0) {
      gr0 = perm[row0 + min(lr0, valid - 1)] >> 1;
      gr1 = perm[row0 + min(lr1, valid - 1)] >> 1;
    } else if constexpr (MODE == 1) {
      gr0 = row0 + min(lr0, valid - 1);
      gr1 = row0 + min(lr1, valid - 1);
    } else {
      gr0 = row0 + lr0;
      gr1 = row0 + lr1;
    }
    aSrc0 = A + (size_t)gr0 * K + sc * 8;
    aSrc1 = A + (size_t)gr1 * K + sc * 8;
    bSrc0 = Bexp + (size_t)(nt * 256 + srow) * K + sc * 8;
    bSrc1 = Bexp + (size_t)(nt * 256 + 128 + srow) * K + sc * 8;
  }
  bf16_t* const dst0 = lds + (t << 3);

  // ---- fragment read offsets (conflict-free: chunk = quarter ^ (row&3))
  const int rchunk = ((lane >> 4) ^ (lane & 3)) << 3;
  const int aoff = ((wm << 7) + (lane & 15)) * 32 + rchunk;
  const int boff = ((wn << 6) + (lane & 15)) * 32 + rchunk + 8192;

  f32x4 acc[8][4];
#pragma unroll
  for (int m = 0; m < 8; ++m)
#pragma unroll
    for (int n = 0; n < 4; ++n) acc[m][n] = f32x4{0.f, 0.f, 0.f, 0.f};

  auto STAGE = [&](int j) {
    const int kof = j * 32;
    bf16_t* base = dst0 + ((j & 3) << 14);
    GLL(aSrc0 + kof, base);
    GLL(aSrc1 + kof, base + 4096);
    GLL(bSrc0 + kof, base + 8192);
    GLL(bSrc1 + kof, base + 12288);
  };

  // prologue: 3 K-tiles in flight
  STAGE(0); STAGE(1); STAGE(2);

  for (int kt = 0; kt < NK; ++kt) {
    // wait for stage(kt) to land (2 tiles = 8 loads may stay in flight)
    if (kt <= NK - 3)      asm volatile("s_waitcnt vmcnt(8)" ::: "memory");
    else if (kt == NK - 2) asm volatile("s_waitcnt vmcnt(4)" ::: "memory");
    else                   asm volatile("s_waitcnt vmcnt(0)" ::: "memory");
    __builtin_amdgcn_s_barrier();
    // stage kt+3 into buf[(kt-1)&3] (reads of it completed before this barrier)
    if (kt + 3 < NK) STAGE(kt + 3);

    const bf16_t* Lb = lds + ((kt & 3) << 14);
    bf16x8 af[8], bfr[4];
#pragma unroll
    for (int m = 0; m < 8; ++m)
      af[m] = *reinterpret_cast<const bf16x8*>(Lb + aoff + m * 512);
#pragma unroll
    for (int n = 0; n < 4; ++n)
      bfr[n] = *reinterpret_cast<const bf16x8*>(Lb + boff + n * 512);

    __builtin_amdgcn_s_setprio(1);
#pragma unroll
    for (int m = 0; m < 8; ++m)
#pragma unroll
      for (int n = 0; n < 4; ++n)
        acc[m][n] = __builtin_amdgcn_mfma_f32_16x16x32_bf16(af[m], bfr[n], acc[m][n], 0, 0, 0);
    __builtin_amdgcn_s_setprio(0);
  }

  // ---- epilogue.  C/D: col = lane&15, row = (lane>>4)*4 + reg
  if constexpr (G1) {
#pragma unroll
    for (int n = 0; n < 4; ++n) {
      int col = nt * 256 + wn * 64 + n * 16 + (lane & 15);
      float bc = biasp[col];
#pragma unroll
      for (int m = 0; m < 8; ++m) {
        int lrb = wm * 128 + m * 16 + ((lane >> 4) << 2);
#pragma unroll
        for (int rr = 0; rr < 4; ++rr) {
          int lr = lrb + rr;
          if (lr < valid) {
            float v = acc[m][n][rr] + bc;
            Hout[(size_t)(row0 + lr) * FF + col] = (bf16_t)fast_gelu(v);
          }
        }
      }
    }
  } else {
#pragma unroll
    for (int m = 0; m < 8; ++m) {
      int lrb = wm * 128 + m * 16 + ((lane >> 4) << 2);
#pragma unroll
      for (int rr = 0; rr < 4; ++rr) {
        int lr = lrb + rr;
        if (lr >= valid) continue;
#pragma unroll
        for (int n = 0; n < 4; ++n) {
          int col = nt * 256 + wn * 64 + n * 16 + (lane & 15);
          out[(size_t)(row0 + lr) * DD + col] = acc[m][n][rr] + biasp[col];
        }
      }
    }
  }
}

// ---------------------------------------------------------------- launch
extern "C" void kernel_launch(void* const* d_in, const int* in_sizes, int n_in,
                              void* d_out, int out_size, void* d_ws, size_t ws_size,
                              hipStream_t stream) {
  const float* x   = (const float*)d_in[0];
  const float* gw  = (const float*)d_in[1];
  const float* w1  = (const float*)d_in[2];
  const float* b1  = (const float*)d_in[3];
  const float* w2  = (const float*)d_in[4];
  const float* b2  = (const float*)d_in[5];
  const float* sw1 = (const float*)d_in[6];
  const float* sb1 = (const float*)d_in[7];
  const float* sw2 = (const float*)d_in[8];
  const float* sb2 = (const float*)d_in[9];
  float* out = (float*)d_out;

  char* ws = (char*)d_ws;
  bf16_t* xb    = (bf16_t*)(ws);                          // 16 MB  [dead after expert G1]
  bf16_t* w1b   = (bf16_t*)(ws + ((size_t)16 << 20));     // 64 MB  [dead after expert G1]
  bf16_t* w2b   = (bf16_t*)(ws + ((size_t)80 << 20));     // 64 MB
  bf16_t* sw1b  = (bf16_t*)(ws + ((size_t)144 << 20));    // 8 MB
  bf16_t* sw2b  = (bf16_t*)(ws + ((size_t)152 << 20));    // 8 MB
  bf16_t* Hbuf  = (bf16_t*)(ws + ((size_t)160 << 20));    // 128 MB (16384 x 4096 bf16)
  float*  slotbuf = (float*)(ws);                         // 67 MB, overlaps xb+w1b (dead by then)
  float*  topkw = (float*)(ws + ((size_t)288 << 20));     // 64 KB
  int*    slote = (int*)(ws + ((size_t)288 << 20) + 65536);
  int*    perm  = (int*)(ws + ((size_t)288 << 20) + 2 * 65536);
  int*    pos   = (int*)(ws + ((size_t)288 << 20) + 3 * 65536);
  int*    routing = (int*)(ws + ((size_t)288 << 20) + 4 * 65536);

  hipMemsetAsync(routing, 0, R_INTS * sizeof(int), stream);

  // fp32 -> bf16 conversions
  cvt_f32_bf16<<<(TT * DD / 8 + 255) / 256, 256, 0, stream>>>(x, xb, TT * DD / 8);
  cvt_f32_bf16<<<(8 * FF * DD / 8 + 255) / 256, 256, 0, stream>>>(w1, w1b, 8 * FF * DD / 8);
  cvt_f32_bf16<<<(8 * DD * FF / 8 + 255) / 256, 256, 0, stream>>>(w2, w2b, 8 * DD * FF / 8);
  cvt_f32_bf16<<<(FF * DD / 8 + 255) / 256, 256, 0, stream>>>(sw1, sw1b, FF * DD / 8);
  cvt_f32_bf16<<<(DD * FF / 8 + 255) / 256, 256, 0, stream>>>(sw2, sw2b, DD * FF / 8);

  // routing
  gate_kernel<<<TT / 4, 256, 0, stream>>>(x, gw, topkw, slote, routing);
  scan_kernel<<<1, 1, 0, stream>>>(routing);
  scatter_kernel<<<NSLOT / 256, 256, 0, stream>>>(slote, routing, perm, pos);

  // shared expert first (plain store covers all of out), then experts into slotbuf
  gemm_kernel<2><<<32 * 16, 512, 0, stream>>>(xb, sw1b, sb1, Hbuf, out, routing, perm);
  gemm_kernel<3><<<32 * 4, 512, 0, stream>>>(Hbuf, sw2b, sb2, nullptr, out, routing, perm);
  gemm_kernel<0><<<72 * 16, 512, 0, stream>>>(xb, w1b, b1, Hbuf, out, routing, perm);
  gemm_kernel<1><<<72 * 4, 512, 0, stream>>>(Hbuf, w2b, b2, nullptr, slotbuf, routing, perm);

  // out += gate-weighted expert contributions
  combine_kernel<<<TT, 256, 0, stream>>>(slotbuf, pos, topkw, out);
}

// Round 4
// 1103.358 us; speedup vs baseline: 1.2015x; 1.0302x over previous
//
#include <hip/hip_runtime.h>
#include <hip/hip_bf16.h>

typedef __bf16 bf16_t;
typedef __bf16 bf16x8 __attribute__((ext_vector_type(8)));
typedef float  f32x4  __attribute__((ext_vector_type(4)));

static constexpr int TT = 8192;     // tokens (2*4096)
static constexpr int DD = 1024;
static constexpr int FF = 4096;
static constexpr int NSLOT = 2 * TT;  // 16384 (token, k) slots

// routing int-array layout
#define R_COUNTS 0
#define R_OFFSET 8
#define R_TSTART 17
#define R_CURSOR 26
#define R_TOTAL  34
#define R_INTS   40

#define GLL(g, l) __builtin_amdgcn_global_load_lds( \
    (__attribute__((address_space(1))) void*)(g), \
    (__attribute__((address_space(3))) void*)(l), 16, 0, 0)

__device__ __forceinline__ float fast_gelu(float v) {
  float t = -1.5957691216f * v - 0.0713548162f * (v * v * v);
  return v / (1.f + __expf(t));
}

// ---------------------------------------------------------------- convert
__global__ __launch_bounds__(256) void cvt_f32_bf16(const float* __restrict__ src,
                                                    bf16_t* __restrict__ dst, int n8) {
  int i = blockIdx.x * 256 + threadIdx.x;
  if (i >= n8) return;
  const float4* s = reinterpret_cast<const float4*>(src) + (size_t)i * 2;
  float4 a = s[0], b = s[1];
  bf16x8 v;
  v[0] = (bf16_t)a.x; v[1] = (bf16_t)a.y; v[2] = (bf16_t)a.z; v[3] = (bf16_t)a.w;
  v[4] = (bf16_t)b.x; v[5] = (bf16_t)b.y; v[6] = (bf16_t)b.z; v[7] = (bf16_t)b.w;
  *reinterpret_cast<bf16x8*>(dst + (size_t)i * 8) = v;
}

// ---------------------------------------------------------------- gate
__global__ __launch_bounds__(256) void gate_kernel(const float* __restrict__ x,
                                                   const float* __restrict__ gw,
                                                   float* __restrict__ topkw,
                                                   int* __restrict__ slote,
                                                   int* __restrict__ routing) {
  int wid = threadIdx.x >> 6, lane = threadIdx.x & 63;
  int t = blockIdx.x * 4 + wid;
  const float4* xv = reinterpret_cast<const float4*>(x + (size_t)t * DD) + lane * 4;
  const float4* gv = reinterpret_cast<const float4*>(gw);
  float acc[8];
#pragma unroll
  for (int e = 0; e < 8; ++e) acc[e] = 0.f;
#pragma unroll
  for (int i = 0; i < 4; ++i) {
    float4 xi = xv[i];
#pragma unroll
    for (int e = 0; e < 8; ++e) {
      float4 g = gv[e * 256 + lane * 4 + i];
      acc[e] += xi.x * g.x + xi.y * g.y + xi.z * g.z + xi.w * g.w;
    }
  }
#pragma unroll
  for (int e = 0; e < 8; ++e)
    for (int off = 32; off; off >>= 1) acc[e] += __shfl_xor(acc[e], off, 64);
  if (lane == 0) {
    float m = acc[0];
#pragma unroll
    for (int e = 1; e < 8; ++e) m = fmaxf(m, acc[e]);
    float p[8], s = 0.f;
#pragma unroll
    for (int e = 0; e < 8; ++e) { p[e] = expf(acc[e] - m); s += p[e]; }
    float inv = 1.f / s;
#pragma unroll
    for (int e = 0; e < 8; ++e) p[e] *= inv;
    int e1 = 0; float b1v = p[0];
#pragma unroll
    for (int e = 1; e < 8; ++e) if (p[e] > b1v) { b1v = p[e]; e1 = e; }
    int e2 = -1; float b2v = -1.f;
#pragma unroll
    for (int e = 0; e < 8; ++e) if (e != e1 && p[e] > b2v) { b2v = p[e]; e2 = e; }
    topkw[2 * t] = b1v;  topkw[2 * t + 1] = b2v;
    slote[2 * t] = e1;   slote[2 * t + 1] = e2;
    atomicAdd(&routing[R_COUNTS + e1], 1);
    atomicAdd(&routing[R_COUNTS + e2], 1);
  }
}

// ---------------------------------------------------------------- scan (1 thread)
__global__ void scan_kernel(int* __restrict__ routing) {
  int off = 0, tt = 0;
  for (int e = 0; e < 8; ++e) {
    routing[R_OFFSET + e] = off;
    routing[R_TSTART + e] = tt;
    int c = routing[R_COUNTS + e];
    off += c;
    tt += (c + 255) >> 8;   // 256-row M-tiles
    routing[R_CURSOR + e] = 0;
  }
  routing[R_OFFSET + 8] = off;
  routing[R_TSTART + 8] = tt;
  routing[R_TOTAL] = tt;
}

// ---------------------------------------------------------------- scatter
__global__ __launch_bounds__(256) void scatter_kernel(const int* __restrict__ slote,
                                                      int* __restrict__ routing,
                                                      int* __restrict__ perm,
                                                      int* __restrict__ pos) {
  int s = blockIdx.x * 256 + threadIdx.x;
  int e = slote[s];
  int p = atomicAdd(&routing[R_CURSOR + e], 1);
  int pp = routing[R_OFFSET + e] + p;
  perm[pp] = s;
  pos[s] = pp;
}

// ---------------------------------------------------------------- combine
__global__ __launch_bounds__(256) void combine_kernel(const float* __restrict__ slotbuf,
                                                      const int* __restrict__ pos,
                                                      const float* __restrict__ topkw,
                                                      float* __restrict__ out) {
  int idx = blockIdx.x * 256 + threadIdx.x;   // one float4 per thread
  int t = idx >> 8;                            // DD/4 = 256 float4 per token
  int c = (idx & 255) << 2;
  int p0 = pos[2 * t], p1 = pos[2 * t + 1];
  float w0 = topkw[2 * t], w1 = topkw[2 * t + 1];
  float4 o = *reinterpret_cast<const float4*>(&out[(size_t)t * DD + c]);
  float4 s0 = *reinterpret_cast<const float4*>(&slotbuf[(size_t)p0 * DD + c]);
  float4 s1 = *reinterpret_cast<const float4*>(&slotbuf[(size_t)p1 * DD + c]);
  o.x += w0 * s0.x + w1 * s1.x;
  o.y += w0 * s0.y + w1 * s1.y;
  o.z += w0 * s0.z + w1 * s1.z;
  o.w += w0 * s0.w + w1 * s1.w;
  *reinterpret_cast<float4*>(&out[(size_t)t * DD + c]) = o;
}

// ---------------------------------------------------------------- GEMM (pipelined 256x256, BK=32, ring-4)
// MODE 0: expert G1 (A gathered via perm, K=1024) -> fast_gelu -> H (bf16)
// MODE 1: expert G2 (A = H rows, K=4096)          -> (.+b2) store slotbuf fp32
// MODE 2: shared G1 (A = x direct, K=1024)        -> fast_gelu -> H (bf16)
// MODE 3: shared G2 (A = H rows, K=4096)          -> plain store out (+sb2)
//
// LDS swizzle (conflict-free for 64B row stride): phys_chunk = log_chunk ^ ((row>>1)&3)
//   bank(lane) = (lane&1)*16 + ((lane>>1)&3)*4 -> each of 8 bank-quads hit exactly
//   2x per 16-lane group = 2-way = free [m136]. Applied on BOTH sides (rule #21):
//   pre-swizzled global source for the linear global_load_lds dest + swizzled ds_read.
template <int MODE>
__global__ __launch_bounds__(512, 2) void gemm_kernel(
    const bf16_t* __restrict__ A, const bf16_t* __restrict__ Bw,
    const float* __restrict__ bias, bf16_t* __restrict__ Hout,
    float* __restrict__ out, const int* __restrict__ routing,
    const int* __restrict__ perm) {
  constexpr bool G1 = (MODE == 0 || MODE == 2);
  constexpr bool EXPERT = (MODE < 2);
  constexpr int K = G1 ? 1024 : 4096;
  constexpr int NTOT = G1 ? 4096 : 1024;
  constexpr int NT = NTOT / 256;   // 16 or 4
  constexpr int NK = K / 32;       // 32 or 128

  // ring of 4 buffers: [buf][A:256x32 | B:256x32] bf16 = 4 * 32KB = 128KB
  __shared__ __align__(16) bf16_t lds[4 * 16384];

  const int t = threadIdx.x;
  const int lane = t & 63;
  const int wid = t >> 6;          // 0..7
  const int wm = wid >> 2;         // 0..1  (128-row half)
  const int wn = wid & 3;          // 0..3  (64-col quarter)

  // ---- block decode: bijective XCD swizzle, nt-fastest
  const int nwg = gridDim.x;
  const int q = nwg >> 3, r = nwg & 7;
  const int xcd = blockIdx.x & 7, bi = blockIdx.x >> 3;
  const int swz = (xcd < r ? xcd * (q + 1) : r * (q + 1) + (xcd - r) * q) + bi;
  const int mt = swz / NT;
  const int nt = swz % NT;

  int row0, valid, eidx = 0;
  if constexpr (EXPERT) {
    if (mt >= routing[R_TOTAL]) return;
    int e = 0;
    while (e < 7 && routing[R_TSTART + e + 1] <= mt) ++e;
    eidx = e;
    int lm = mt - routing[R_TSTART + e];
    row0 = routing[R_OFFSET + e] + lm * 256;
    valid = min(256, routing[R_COUNTS + e] - lm * 256);
  } else {
    row0 = mt * 256;
    valid = 256;
  }

  const bf16_t* Bexp = Bw + (EXPERT ? (size_t)eidx * NTOT * K : 0);
  const float* biasp = bias + (EXPERT ? eidx * NTOT : 0);

  // ---- staging source pointers. thread t covers (row = t>>2, phys chunk = t&3)
  // source (logical) chunk = (t&3) ^ ((row>>1)&3) = (t&3) ^ ((t>>3)&3)
  const int srow = t >> 2;
  const int sc = (t & 3) ^ ((t >> 3) & 3);
  const bf16_t *aSrc0, *aSrc1, *bSrc0, *bSrc1;
  {
    int lr0 = srow, lr1 = 128 + srow;
    int gr0, gr1;
    if constexpr (MODE == 0) {
      gr0 = perm[row0 + min(lr0, valid - 1)] >> 1;
      gr1 = perm[row0 + min(lr1, valid - 1)] >> 1;
    } else if constexpr (MODE == 1) {
      gr0 = row0 + min(lr0, valid - 1);
      gr1 = row0 + min(lr1, valid - 1);
    } else {
      gr0 = row0 + lr0;
      gr1 = row0 + lr1;
    }
    aSrc0 = A + (size_t)gr0 * K + sc * 8;
    aSrc1 = A + (size_t)gr1 * K + sc * 8;
    bSrc0 = Bexp + (size_t)(nt * 256 + srow) * K + sc * 8;
    bSrc1 = Bexp + (size_t)(nt * 256 + 128 + srow) * K + sc * 8;
  }
  bf16_t* const dst0 = lds + (t << 3);

  // ---- fragment read offsets: logical chunk = lane>>4, row low bits = lane&15
  // phys chunk = (lane>>4) ^ ((row>>1)&3) = (lane>>4) ^ ((lane>>1)&3)
  const int rchunk = ((lane >> 4) ^ ((lane >> 1) & 3)) << 3;
  const int aoff = ((wm << 7) + (lane & 15)) * 32 + rchunk;
  const int boff = ((wn << 6) + (lane & 15)) * 32 + rchunk + 8192;

  f32x4 acc[8][4];
#pragma unroll
  for (int m = 0; m < 8; ++m)
#pragma unroll
    for (int n = 0; n < 4; ++n) acc[m][n] = f32x4{0.f, 0.f, 0.f, 0.f};

  auto STAGE = [&](int j) {
    const int kof = j * 32;
    bf16_t* base = dst0 + ((j & 3) << 14);
    GLL(aSrc0 + kof, base);
    GLL(aSrc1 + kof, base + 4096);
    GLL(bSrc0 + kof, base + 8192);
    GLL(bSrc1 + kof, base + 12288);
  };

  // prologue: 3 K-tiles in flight
  STAGE(0); STAGE(1); STAGE(2);

  for (int kt = 0; kt < NK; ++kt) {
    // wait for stage(kt) to land (2 tiles = 8 loads may stay in flight)
    if (kt <= NK - 3)      asm volatile("s_waitcnt vmcnt(8)" ::: "memory");
    else if (kt == NK - 2) asm volatile("s_waitcnt vmcnt(4)" ::: "memory");
    else                   asm volatile("s_waitcnt vmcnt(0)" ::: "memory");
    __builtin_amdgcn_s_barrier();
    // stage kt+3 into buf[(kt-1)&3] (reads of it completed before this barrier)
    if (kt + 3 < NK) STAGE(kt + 3);

    const bf16_t* Lb = lds + ((kt & 3) << 14);
    bf16x8 af[8], bfr[4];
#pragma unroll
    for (int m = 0; m < 8; ++m)
      af[m] = *reinterpret_cast<const bf16x8*>(Lb + aoff + m * 512);
#pragma unroll
    for (int n = 0; n < 4; ++n)
      bfr[n] = *reinterpret_cast<const bf16x8*>(Lb + boff + n * 512);

    __builtin_amdgcn_s_setprio(1);
#pragma unroll
    for (int m = 0; m < 8; ++m)
#pragma unroll
      for (int n = 0; n < 4; ++n)
        acc[m][n] = __builtin_amdgcn_mfma_f32_16x16x32_bf16(af[m], bfr[n], acc[m][n], 0, 0, 0);
    __builtin_amdgcn_s_setprio(0);
  }

  // ---- epilogue.  C/D: col = lane&15, row = (lane>>4)*4 + reg
  if constexpr (G1) {
#pragma unroll
    for (int n = 0; n < 4; ++n) {
      int col = nt * 256 + wn * 64 + n * 16 + (lane & 15);
      float bc = biasp[col];
#pragma unroll
      for (int m = 0; m < 8; ++m) {
        int lrb = wm * 128 + m * 16 + ((lane >> 4) << 2);
#pragma unroll
        for (int rr = 0; rr < 4; ++rr) {
          int lr = lrb + rr;
          if (lr < valid) {
            float v = acc[m][n][rr] + bc;
            Hout[(size_t)(row0 + lr) * FF + col] = (bf16_t)fast_gelu(v);
          }
        }
      }
    }
  } else {
#pragma unroll
    for (int m = 0; m < 8; ++m) {
      int lrb = wm * 128 + m * 16 + ((lane >> 4) << 2);
#pragma unroll
      for (int rr = 0; rr < 4; ++rr) {
        int lr = lrb + rr;
        if (lr >= valid) continue;
#pragma unroll
        for (int n = 0; n < 4; ++n) {
          int col = nt * 256 + wn * 64 + n * 16 + (lane & 15);
          out[(size_t)(row0 + lr) * DD + col] = acc[m][n][rr] + biasp[col];
        }
      }
    }
  }
}

// ---------------------------------------------------------------- launch
extern "C" void kernel_launch(void* const* d_in, const int* in_sizes, int n_in,
                              void* d_out, int out_size, void* d_ws, size_t ws_size,
                              hipStream_t stream) {
  const float* x   = (const float*)d_in[0];
  const float* gw  = (const float*)d_in[1];
  const float* w1  = (const float*)d_in[2];
  const float* b1  = (const float*)d_in[3];
  const float* w2  = (const float*)d_in[4];
  const float* b2  = (const float*)d_in[5];
  const float* sw1 = (const float*)d_in[6];
  const float* sb1 = (const float*)d_in[7];
  const float* sw2 = (const float*)d_in[8];
  const float* sb2 = (const float*)d_in[9];
  float* out = (float*)d_out;

  char* ws = (char*)d_ws;
  bf16_t* xb    = (bf16_t*)(ws);                          // 16 MB  [dead after expert G1]
  bf16_t* w1b   = (bf16_t*)(ws + ((size_t)16 << 20));     // 64 MB  [dead after expert G1]
  bf16_t* w2b   = (bf16_t*)(ws + ((size_t)80 << 20));     // 64 MB
  bf16_t* sw1b  = (bf16_t*)(ws + ((size_t)144 << 20));    // 8 MB
  bf16_t* sw2b  = (bf16_t*)(ws + ((size_t)152 << 20));    // 8 MB
  bf16_t* Hbuf  = (bf16_t*)(ws + ((size_t)160 << 20));    // 128 MB (16384 x 4096 bf16)
  float*  slotbuf = (float*)(ws);                         // 67 MB, overlaps xb+w1b (dead by then)
  float*  topkw = (float*)(ws + ((size_t)288 << 20));     // 64 KB
  int*    slote = (int*)(ws + ((size_t)288 << 20) + 65536);
  int*    perm  = (int*)(ws + ((size_t)288 << 20) + 2 * 65536);
  int*    pos   = (int*)(ws + ((size_t)288 << 20) + 3 * 65536);
  int*    routing = (int*)(ws + ((size_t)288 << 20) + 4 * 65536);

  hipMemsetAsync(routing, 0, R_INTS * sizeof(int), stream);

  // fp32 -> bf16 conversions
  cvt_f32_bf16<<<(TT * DD / 8 + 255) / 256, 256, 0, stream>>>(x, xb, TT * DD / 8);
  cvt_f32_bf16<<<(8 * FF * DD / 8 + 255) / 256, 256, 0, stream>>>(w1, w1b, 8 * FF * DD / 8);
  cvt_f32_bf16<<<(8 * DD * FF / 8 + 255) / 256, 256, 0, stream>>>(w2, w2b, 8 * DD * FF / 8);
  cvt_f32_bf16<<<(FF * DD / 8 + 255) / 256, 256, 0, stream>>>(sw1, sw1b, FF * DD / 8);
  cvt_f32_bf16<<<(DD * FF / 8 + 255) / 256, 256, 0, stream>>>(sw2, sw2b, DD * FF / 8);

  // routing
  gate_kernel<<<TT / 4, 256, 0, stream>>>(x, gw, topkw, slote, routing);
  scan_kernel<<<1, 1, 0, stream>>>(routing);
  scatter_kernel<<<NSLOT / 256, 256, 0, stream>>>(slote, routing, perm, pos);

  // shared expert first (plain store covers all of out), then experts into slotbuf
  gemm_kernel<2><<<32 * 16, 512, 0, stream>>>(xb, sw1b, sb1, Hbuf, out, routing, perm);
  gemm_kernel<3><<<32 * 4, 512, 0, stream>>>(Hbuf, sw2b, sb2, nullptr, out, routing, perm);
  gemm_kernel<0><<<72 * 16, 512, 0, stream>>>(xb, w1b, b1, Hbuf, out, routing, perm);
  gemm_kernel<1><<<72 * 4, 512, 0, stream>>>(Hbuf, w2b, b2, nullptr, slotbuf, routing, perm);

  // out += gate-weighted expert contributions
  combine_kernel<<<TT, 256, 0, stream>>>(slotbuf, pos, topkw, out);
}

// Round 5
// 1066.805 us; speedup vs baseline: 1.2427x; 1.0343x over previous
//
#include <hip/hip_runtime.h>
#include <hip/hip_bf16.h>

typedef __bf16 bf16_t;
typedef __bf16 bf16x8 __attribute__((ext_vector_type(8)));
typedef float  f32x4  __attribute__((ext_vector_type(4)));

static constexpr int TT = 8192;     // tokens (2*4096)
static constexpr int DD = 1024;
static constexpr int FF = 4096;
static constexpr int NSLOT = 2 * TT;  // 16384 (token, k) slots

// routing int-array layout
#define R_COUNTS 0
#define R_OFFSET 8
#define R_TSTART 17
#define R_CURSOR 26
#define R_TOTAL  34
#define R_INTS   40

#define GLL(g, l) __builtin_amdgcn_global_load_lds( \
    (__attribute__((address_space(1))) void*)(g), \
    (__attribute__((address_space(3))) void*)(l), 16, 0, 0)

#define BARRIER asm volatile("s_barrier" ::: "memory")
#define WAITL0  do { asm volatile("s_waitcnt lgkmcnt(0)" ::: "memory"); \
                     __builtin_amdgcn_sched_barrier(0); } while (0)

__device__ __forceinline__ float fast_gelu(float v) {
  float t = -1.5957691216f * v - 0.0713548162f * (v * v * v);
  return v / (1.f + __expf(t));
}

// ---------------------------------------------------------------- convert
__global__ __launch_bounds__(256) void cvt_f32_bf16(const float* __restrict__ src,
                                                    bf16_t* __restrict__ dst, int n8) {
  int i = blockIdx.x * 256 + threadIdx.x;
  if (i >= n8) return;
  const float4* s = reinterpret_cast<const float4*>(src) + (size_t)i * 2;
  float4 a = s[0], b = s[1];
  bf16x8 v;
  v[0] = (bf16_t)a.x; v[1] = (bf16_t)a.y; v[2] = (bf16_t)a.z; v[3] = (bf16_t)a.w;
  v[4] = (bf16_t)b.x; v[5] = (bf16_t)b.y; v[6] = (bf16_t)b.z; v[7] = (bf16_t)b.w;
  *reinterpret_cast<bf16x8*>(dst + (size_t)i * 8) = v;
}

// ---------------------------------------------------------------- gate
__global__ __launch_bounds__(256) void gate_kernel(const float* __restrict__ x,
                                                   const float* __restrict__ gw,
                                                   float* __restrict__ topkw,
                                                   int* __restrict__ slote,
                                                   int* __restrict__ routing) {
  int wid = threadIdx.x >> 6, lane = threadIdx.x & 63;
  int t = blockIdx.x * 4 + wid;
  const float4* xv = reinterpret_cast<const float4*>(x + (size_t)t * DD) + lane * 4;
  const float4* gv = reinterpret_cast<const float4*>(gw);
  float acc[8];
#pragma unroll
  for (int e = 0; e < 8; ++e) acc[e] = 0.f;
#pragma unroll
  for (int i = 0; i < 4; ++i) {
    float4 xi = xv[i];
#pragma unroll
    for (int e = 0; e < 8; ++e) {
      float4 g = gv[e * 256 + lane * 4 + i];
      acc[e] += xi.x * g.x + xi.y * g.y + xi.z * g.z + xi.w * g.w;
    }
  }
#pragma unroll
  for (int e = 0; e < 8; ++e)
    for (int off = 32; off; off >>= 1) acc[e] += __shfl_xor(acc[e], off, 64);
  if (lane == 0) {
    float m = acc[0];
#pragma unroll
    for (int e = 1; e < 8; ++e) m = fmaxf(m, acc[e]);
    float p[8], s = 0.f;
#pragma unroll
    for (int e = 0; e < 8; ++e) { p[e] = expf(acc[e] - m); s += p[e]; }
    float inv = 1.f / s;
#pragma unroll
    for (int e = 0; e < 8; ++e) p[e] *= inv;
    int e1 = 0; float b1v = p[0];
#pragma unroll
    for (int e = 1; e < 8; ++e) if (p[e] > b1v) { b1v = p[e]; e1 = e; }
    int e2 = -1; float b2v = -1.f;
#pragma unroll
    for (int e = 0; e < 8; ++e) if (e != e1 && p[e] > b2v) { b2v = p[e]; e2 = e; }
    topkw[2 * t] = b1v;  topkw[2 * t + 1] = b2v;
    slote[2 * t] = e1;   slote[2 * t + 1] = e2;
    atomicAdd(&routing[R_COUNTS + e1], 1);
    atomicAdd(&routing[R_COUNTS + e2], 1);
  }
}

// ---------------------------------------------------------------- scan (1 thread)
__global__ void scan_kernel(int* __restrict__ routing) {
  int off = 0, tt = 0;
  for (int e = 0; e < 8; ++e) {
    routing[R_OFFSET + e] = off;
    routing[R_TSTART + e] = tt;
    int c = routing[R_COUNTS + e];
    off += c;
    tt += (c + 255) >> 8;   // 256-row M-tiles
    routing[R_CURSOR + e] = 0;
  }
  routing[R_OFFSET + 8] = off;
  routing[R_TSTART + 8] = tt;
  routing[R_TOTAL] = tt;
}

// ---------------------------------------------------------------- scatter
__global__ __launch_bounds__(256) void scatter_kernel(const int* __restrict__ slote,
                                                      int* __restrict__ routing,
                                                      int* __restrict__ perm,
                                                      int* __restrict__ pos) {
  int s = blockIdx.x * 256 + threadIdx.x;
  int e = slote[s];
  int p = atomicAdd(&routing[R_CURSOR + e], 1);
  int pp = routing[R_OFFSET + e] + p;
  perm[pp] = s;
  pos[s] = pp;
}

// ---------------------------------------------------------------- combine
__global__ __launch_bounds__(256) void combine_kernel(const float* __restrict__ slotbuf,
                                                      const int* __restrict__ pos,
                                                      const float* __restrict__ topkw,
                                                      float* __restrict__ out) {
  int idx = blockIdx.x * 256 + threadIdx.x;   // one float4 per thread
  int t = idx >> 8;                            // DD/4 = 256 float4 per token
  int c = (idx & 255) << 2;
  int p0 = pos[2 * t], p1 = pos[2 * t + 1];
  float w0 = topkw[2 * t], w1 = topkw[2 * t + 1];
  float4 o = *reinterpret_cast<const float4*>(&out[(size_t)t * DD + c]);
  float4 s0 = *reinterpret_cast<const float4*>(&slotbuf[(size_t)p0 * DD + c]);
  float4 s1 = *reinterpret_cast<const float4*>(&slotbuf[(size_t)p1 * DD + c]);
  o.x += w0 * s0.x + w1 * s1.x;
  o.y += w0 * s0.y + w1 * s1.y;
  o.z += w0 * s0.z + w1 * s1.z;
  o.w += w0 * s0.w + w1 * s1.w;
  *reinterpret_cast<float4*>(&out[(size_t)t * DD + c]) = o;
}

// ---------------------------------------------------------------- GEMM (8-phase 256x256, BK=64, dbuf)
// MODE 0: expert G1 (A gathered via perm, K=1024) -> fast_gelu -> H (bf16)
// MODE 1: expert G2 (A = H rows, K=4096)          -> (.+b2) store slotbuf fp32
// MODE 2: shared G1 (A = x direct, K=1024)        -> fast_gelu -> H (bf16)
// MODE 3: shared G2 (A = H rows, K=4096)          -> plain store out (+sb2)
//
// LDS per buffer: A 256x64 (two 128-row halves) + B 256x64 = 64 KB; 2 buffers = 128 KB.
// Row = 128 B = 8 chunks of 16 B; swizzle phys_chunk = log_chunk ^ (row&7), both sides.
// Schedule per K-tile kt (4 phases): phase p reads its A/B subtile, stages one half-tile
// (p0: A-low(kt+1), p1: A-high(kt+1) -> other buf; p2: B-low(kt+2), p3: B-high(kt+2) ->
// current buf, safe: B(kt) fully read in phase 0, >=2 barriers before). vmcnt(4) at each
// K-tile end keeps 2 half-tiles in flight (never drains to 0 mid-loop).
template <int MODE>
__global__ __launch_bounds__(512, 2) void gemm_kernel(
    const bf16_t* __restrict__ A, const bf16_t* __restrict__ Bw,
    const float* __restrict__ bias, bf16_t* __restrict__ Hout,
    float* __restrict__ out, const int* __restrict__ routing,
    const int* __restrict__ perm) {
  constexpr bool G1 = (MODE == 0 || MODE == 2);
  constexpr bool EXPERT = (MODE < 2);
  constexpr int K = G1 ? 1024 : 4096;
  constexpr int NTOT = G1 ? 4096 : 1024;
  constexpr int NT = NTOT / 256;   // 16 or 4
  constexpr int NKT = K / 64;      // 16 or 64

  __shared__ __align__(16) bf16_t lds[2 * 32768];   // 128 KB

  const int t = threadIdx.x;
  const int lane = t & 63;
  const int wid = t >> 6;          // 0..7
  const int wm = wid >> 2;         // 0..1  (128-row half)
  const int wn = wid & 3;          // 0..3  (64-col quarter)

  // ---- block decode: bijective XCD swizzle, nt-fastest
  const int nwg = gridDim.x;
  const int q = nwg >> 3, r = nwg & 7;
  const int xcd = blockIdx.x & 7, bi = blockIdx.x >> 3;
  const int swz = (xcd < r ? xcd * (q + 1) : r * (q + 1) + (xcd - r) * q) + bi;
  const int mt = swz / NT;
  const int nt = swz % NT;

  int row0, valid, eidx = 0;
  if constexpr (EXPERT) {
    if (mt >= routing[R_TOTAL]) return;
    int e = 0;
    while (e < 7 && routing[R_TSTART + e + 1] <= mt) ++e;
    eidx = e;
    int lm = mt - routing[R_TSTART + e];
    row0 = routing[R_OFFSET + e] + lm * 256;
    valid = min(256, routing[R_COUNTS + e] - lm * 256);
  } else {
    row0 = mt * 256;
    valid = 256;
  }

  const bf16_t* Bexp = Bw + (EXPERT ? (size_t)eidx * NTOT * K : 0);
  const float* biasp = bias + (EXPERT ? eidx * NTOT : 0);

  // ---- staging: half-tile = 128 rows x 64 k = 16 KB = 2 GLL/thread.
  // thread t, GLL g: linear chunk c = g*512 + t; row = c>>3, phys chunk = t&7,
  // logical (source) chunk = (t&7) ^ ((t>>3)&7).
  const int sr = t >> 3;                       // 0..63
  const int lc = (t & 7) ^ ((t >> 3) & 7);
  const bf16_t* aS[4];
  const bf16_t* bS[4];
#pragma unroll
  for (int i = 0; i < 4; ++i) {
    int lr = sr + i * 64;                      // 0..255 within tile
    int gr;
    if constexpr (MODE == 0) {
      gr = perm[row0 + min(lr, valid - 1)] >> 1;
    } else if constexpr (MODE == 1) {
      gr = row0 + min(lr, valid - 1);
    } else {
      gr = row0 + lr;
    }
    aS[i] = A + (size_t)gr * K + lc * 8;
    bS[i] = Bexp + (size_t)(nt * 256 + lr) * K + lc * 8;
  }

  auto stageA = [&](int j, int half) {
    bf16_t* d = lds + ((j & 1) << 15) + (half << 13) + (t << 3);
    size_t kof = (size_t)j * 64;
    GLL(aS[half * 2 + 0] + kof, d);
    GLL(aS[half * 2 + 1] + kof, d + 4096);
  };
  auto stageB = [&](int j, int half) {
    bf16_t* d = lds + ((j & 1) << 15) + 16384 + (half << 13) + (t << 3);
    size_t kof = (size_t)j * 64;
    GLL(bS[half * 2 + 0] + kof, d);
    GLL(bS[half * 2 + 1] + kof, d + 4096);
  };

  // ---- fragment read offsets (elements)
  const int xorv = lane & 7;
  const int kgrp = lane >> 4;
  const int ck0 = ((kgrp) ^ xorv) << 3;
  const int ck1 = ((kgrp + 4) ^ xorv) << 3;
  const int aBase = (wm << 13) + ((lane & 15) << 6);                    // + m*1024 + ck
  const int bBase = 16384 + ((wn >> 1) << 13) + ((wn & 1) << 12) + ((lane & 15) << 6);

  f32x4 acc[8][4];
#pragma unroll
  for (int m = 0; m < 8; ++m)
#pragma unroll
    for (int n = 0; n < 4; ++n) acc[m][n] = f32x4{0.f, 0.f, 0.f, 0.f};

#define PHASE_READ_A(M0)                                                                   \
  _Pragma("unroll") for (int mm = 0; mm < 2; ++mm) {                                       \
    af[mm][0] = *reinterpret_cast<const bf16x8*>(bufp + aBase + (M0 + mm) * 1024 + ck0);   \
    af[mm][1] = *reinterpret_cast<const bf16x8*>(bufp + aBase + (M0 + mm) * 1024 + ck1);   \
  }

#define PHASE_MFMA(M0)                                                                     \
  __builtin_amdgcn_s_setprio(1);                                                           \
  _Pragma("unroll") for (int mm = 0; mm < 2; ++mm)                                         \
  _Pragma("unroll") for (int n = 0; n < 4; ++n) {                                          \
    acc[M0 + mm][n] = __builtin_amdgcn_mfma_f32_16x16x32_bf16(af[mm][0], bfr[n][0],        \
                                                              acc[M0 + mm][n], 0, 0, 0);  \
    acc[M0 + mm][n] = __builtin_amdgcn_mfma_f32_16x16x32_bf16(af[mm][1], bfr[n][1],        \
                                                              acc[M0 + mm][n], 0, 0, 0);  \
  }                                                                                        \
  __builtin_amdgcn_s_setprio(0);

  // ---- prologue: K-tile 0 (A+B) and B of K-tile 1; keep B(1) (4 loads) in flight
  stageA(0, 0); stageA(0, 1);
  stageB(0, 0); stageB(0, 1);
  stageB(1, 0); stageB(1, 1);
  asm volatile("s_waitcnt vmcnt(4)" ::: "memory");
  BARRIER;

  bf16x8 bfr[4][2];
  for (int kt = 0; kt < NKT; ++kt) {
    const bf16_t* bufp = lds + ((kt & 1) << 15);
    bf16x8 af[2][2];

    // phase 0: all B + A m0,m1 (12 ds_reads); stage A-low(kt+1)
#pragma unroll
    for (int n = 0; n < 4; ++n) {
      bfr[n][0] = *reinterpret_cast<const bf16x8*>(bufp + bBase + n * 1024 + ck0);
      bfr[n][1] = *reinterpret_cast<const bf16x8*>(bufp + bBase + n * 1024 + ck1);
    }
    PHASE_READ_A(0)
    if (kt + 1 < NKT) stageA(kt + 1, 0);
    BARRIER; WAITL0;
    PHASE_MFMA(0)
    BARRIER;

    // phase 1: A m2,m3; stage A-high(kt+1)
    PHASE_READ_A(2)
    if (kt + 1 < NKT) stageA(kt + 1, 1);
    BARRIER; WAITL0;
    PHASE_MFMA(2)
    BARRIER;

    // phase 2: A m4,m5; stage B-low(kt+2) into current buffer (B(kt) consumed at phase 0)
    PHASE_READ_A(4)
    if (kt + 2 < NKT) stageB(kt + 2, 0);
    BARRIER; WAITL0;
    PHASE_MFMA(4)
    BARRIER;

    // phase 3: A m6,m7; stage B-high(kt+2); end-of-tile wait (counted, never 0 mid-loop)
    PHASE_READ_A(6)
    if (kt + 2 < NKT) stageB(kt + 2, 1);
    if (kt + 1 < NKT) {
      if (kt + 2 < NKT) { asm volatile("s_waitcnt vmcnt(4)" ::: "memory"); }
      else              { asm volatile("s_waitcnt vmcnt(0)" ::: "memory"); }
    }
    BARRIER; WAITL0;
    PHASE_MFMA(6)
    BARRIER;
  }
#undef PHASE_READ_A
#undef PHASE_MFMA

  // ---- epilogue.  C/D: col = lane&15, row = (lane>>4)*4 + reg
  if constexpr (G1) {
#pragma unroll
    for (int n = 0; n < 4; ++n) {
      int col = nt * 256 + wn * 64 + n * 16 + (lane & 15);
      float bc = biasp[col];
#pragma unroll
      for (int m = 0; m < 8; ++m) {
        int lrb = wm * 128 + m * 16 + ((lane >> 4) << 2);
#pragma unroll
        for (int rr = 0; rr < 4; ++rr) {
          int lr = lrb + rr;
          if (lr < valid) {
            float v = acc[m][n][rr] + bc;
            Hout[(size_t)(row0 + lr) * FF + col] = (bf16_t)fast_gelu(v);
          }
        }
      }
    }
  } else {
#pragma unroll
    for (int m = 0; m < 8; ++m) {
      int lrb = wm * 128 + m * 16 + ((lane >> 4) << 2);
#pragma unroll
      for (int rr = 0; rr < 4; ++rr) {
        int lr = lrb + rr;
        if (lr >= valid) continue;
#pragma unroll
        for (int n = 0; n < 4; ++n) {
          int col = nt * 256 + wn * 64 + n * 16 + (lane & 15);
          out[(size_t)(row0 + lr) * DD + col] = acc[m][n][rr] + biasp[col];
        }
      }
    }
  }
}

// ---------------------------------------------------------------- launch
extern "C" void kernel_launch(void* const* d_in, const int* in_sizes, int n_in,
                              void* d_out, int out_size, void* d_ws, size_t ws_size,
                              hipStream_t stream) {
  const float* x   = (const float*)d_in[0];
  const float* gw  = (const float*)d_in[1];
  const float* w1  = (const float*)d_in[2];
  const float* b1  = (const float*)d_in[3];
  const float* w2  = (const float*)d_in[4];
  const float* b2  = (const float*)d_in[5];
  const float* sw1 = (const float*)d_in[6];
  const float* sb1 = (const float*)d_in[7];
  const float* sw2 = (const float*)d_in[8];
  const float* sb2 = (const float*)d_in[9];
  float* out = (float*)d_out;

  char* ws = (char*)d_ws;
  bf16_t* xb    = (bf16_t*)(ws);                          // 16 MB  [dead after expert G1]
  bf16_t* w1b   = (bf16_t*)(ws + ((size_t)16 << 20));     // 64 MB  [dead after expert G1]
  bf16_t* w2b   = (bf16_t*)(ws + ((size_t)80 << 20));     // 64 MB
  bf16_t* sw1b  = (bf16_t*)(ws + ((size_t)144 << 20));    // 8 MB
  bf16_t* sw2b  = (bf16_t*)(ws + ((size_t)152 << 20));    // 8 MB
  bf16_t* Hbuf  = (bf16_t*)(ws + ((size_t)160 << 20));    // 128 MB (16384 x 4096 bf16)
  float*  slotbuf = (float*)(ws);                         // 67 MB, overlaps xb+w1b (dead by then)
  float*  topkw = (float*)(ws + ((size_t)288 << 20));     // 64 KB
  int*    slote = (int*)(ws + ((size_t)288 << 20) + 65536);
  int*    perm  = (int*)(ws + ((size_t)288 << 20) + 2 * 65536);
  int*    pos   = (int*)(ws + ((size_t)288 << 20) + 3 * 65536);
  int*    routing = (int*)(ws + ((size_t)288 << 20) + 4 * 65536);

  hipMemsetAsync(routing, 0, R_INTS * sizeof(int), stream);

  // fp32 -> bf16 conversions
  cvt_f32_bf16<<<(TT * DD / 8 + 255) / 256, 256, 0, stream>>>(x, xb, TT * DD / 8);
  cvt_f32_bf16<<<(8 * FF * DD / 8 + 255) / 256, 256, 0, stream>>>(w1, w1b, 8 * FF * DD / 8);
  cvt_f32_bf16<<<(8 * DD * FF / 8 + 255) / 256, 256, 0, stream>>>(w2, w2b, 8 * DD * FF / 8);
  cvt_f32_bf16<<<(FF * DD / 8 + 255) / 256, 256, 0, stream>>>(sw1, sw1b, FF * DD / 8);
  cvt_f32_bf16<<<(DD * FF / 8 + 255) / 256, 256, 0, stream>>>(sw2, sw2b, DD * FF / 8);

  // routing
  gate_kernel<<<TT / 4, 256, 0, stream>>>(x, gw, topkw, slote, routing);
  scan_kernel<<<1, 1, 0, stream>>>(routing);
  scatter_kernel<<<NSLOT / 256, 256, 0, stream>>>(slote, routing, perm, pos);

  // shared expert first (plain store covers all of out), then experts into slotbuf
  gemm_kernel<2><<<32 * 16, 512, 0, stream>>>(xb, sw1b, sb1, Hbuf, out, routing, perm);
  gemm_kernel<3><<<32 * 4, 512, 0, stream>>>(Hbuf, sw2b, sb2, nullptr, out, routing, perm);
  gemm_kernel<0><<<72 * 16, 512, 0, stream>>>(xb, w1b, b1, Hbuf, out, routing, perm);
  gemm_kernel<1><<<72 * 4, 512, 0, stream>>>(Hbuf, w2b, b2, nullptr, slotbuf, routing, perm);

  // out += gate-weighted expert contributions
  combine_kernel<<<TT, 256, 0, stream>>>(slotbuf, pos, topkw, out);
}